// Round 1
// baseline (877.054 us; speedup 1.0000x reference)
//
#include <hip/hip_runtime.h>

#define N_NODES 100000
#define N_EDGES 1600000
#define NEG_SLOPE 0.01f

// ---------------------------------------------------------------------------
// deg[i] = 1 (self loop), then += 1 per incoming edge (dst)
// ---------------------------------------------------------------------------
__global__ void k_deg_init(float* __restrict__ deg) {
    int i = blockIdx.x * 256 + threadIdx.x;
    if (i < N_NODES) deg[i] = 1.0f;
}

__global__ void k_deg_count(const int* __restrict__ dst, float* __restrict__ deg) {
    int idx = blockIdx.x * blockDim.x + threadIdx.x;
    int stride = gridDim.x * blockDim.x;
    for (int e = idx; e < N_EDGES; e += stride) {
        atomicAdd(&deg[dst[e]], 1.0f);
    }
}

// ---------------------------------------------------------------------------
// Y[N,64] = (LEAKY? leaky(X) : X)[N,K] @ W[K,64]
// Block: 256 threads, 16 rows/block. W staged in LDS (K*64*4 bytes).
// Thread (rq=tid>>6, c=tid&63) computes rows rq*4..rq*4+3, col c.
// x reads are wave-broadcast float4; w reads are conflict-free stride-1.
// ---------------------------------------------------------------------------
template <int K, bool LEAKY>
__global__ __launch_bounds__(256) void k_gemm(const float* __restrict__ X,
                                              const float* __restrict__ W,
                                              float* __restrict__ Y) {
    __shared__ float ws[K * 64];
    __shared__ __align__(16) float xs[16][K];
    const int tid = threadIdx.x;
    for (int i = tid; i < K * 64; i += 256) ws[i] = W[i];
    const int row0 = blockIdx.x * 16;
    for (int i = tid; i < 16 * K; i += 256) {
        int r = i / K, k = i % K;
        float v = X[(row0 + r) * K + k];
        if (LEAKY) v = (v >= 0.f) ? v : NEG_SLOPE * v;
        xs[r][k] = v;
    }
    __syncthreads();
    const int c = tid & 63, rq = tid >> 6;
    float acc[4] = {0.f, 0.f, 0.f, 0.f};
    const float4* xs4 = reinterpret_cast<const float4*>(&xs[0][0]);
    for (int k = 0; k < K; k += 4) {
        float w0 = ws[(k + 0) * 64 + c];
        float w1 = ws[(k + 1) * 64 + c];
        float w2 = ws[(k + 2) * 64 + c];
        float w3 = ws[(k + 3) * 64 + c];
        const int kq = k >> 2;
#pragma unroll
        for (int j = 0; j < 4; ++j) {
            float4 xv = xs4[(rq * 4 + j) * (K / 4) + kq];
            acc[j] = fmaf(xv.x, w0, acc[j]);
            acc[j] = fmaf(xv.y, w1, acc[j]);
            acc[j] = fmaf(xv.z, w2, acc[j]);
            acc[j] = fmaf(xv.w, w3, acc[j]);
        }
    }
#pragma unroll
    for (int j = 0; j < 4; ++j)
        Y[(row0 + rq * 4 + j) * 64 + c] = acc[j];
}

// ---------------------------------------------------------------------------
// out[i,c] = h[i,c] / deg[i] + b[c]   (self-loop term: dinv[i]^2 = 1/deg[i])
// ---------------------------------------------------------------------------
__global__ void k_selfbias(const float* __restrict__ h, const float* __restrict__ deg,
                           const float* __restrict__ b, float* __restrict__ out) {
    int idx = blockIdx.x * 256 + threadIdx.x;  // exactly N_NODES*64 threads
    int i = idx >> 6, c = idx & 63;
    out[idx] = h[idx] / deg[i] + b[c];
}

// ---------------------------------------------------------------------------
// Edge scatter: out[dst] += h[src] * rsqrt(deg[src]*deg[dst])
// One wave per edge; lane = feature. Grid-stride over edges.
// ---------------------------------------------------------------------------
__global__ void k_edge(const int* __restrict__ src, const int* __restrict__ dst,
                       const float* __restrict__ deg, const float* __restrict__ h,
                       float* __restrict__ out) {
    int gw = (blockIdx.x * blockDim.x + threadIdx.x) >> 6;
    int lane = threadIdx.x & 63;
    int nw = (gridDim.x * blockDim.x) >> 6;
    for (int e = gw; e < N_EDGES; e += nw) {
        int s = src[e], d = dst[e];
        float w = rsqrtf(deg[s] * deg[d]);
        float val = h[s * 64 + lane] * w;
        atomicAdd(&out[d * 64 + lane], val);
    }
}

// ---------------------------------------------------------------------------
// out[N,4] = H[N,64] @ Wfc[64,4] + bfc
// Block: 256 threads, 64 rows/block; H tile staged in LDS (padded stride 65).
// ---------------------------------------------------------------------------
__global__ __launch_bounds__(256) void k_final(const float* __restrict__ H,
                                               const float* __restrict__ Wfc,
                                               const float* __restrict__ bfc,
                                               float* __restrict__ out) {
    __shared__ float ls[64 * 65];
    __shared__ float wl[64 * 4];
    const int tid = threadIdx.x;
    const int row0 = blockIdx.x * 64;
    for (int i = tid; i < 64 * 4; i += 256) wl[i] = Wfc[i];
    for (int i = tid; i < 64 * 64; i += 256) {
        int r = i >> 6, k = i & 63;
        int row = row0 + r;
        ls[r * 65 + k] = (row < N_NODES) ? H[row * 64 + k] : 0.f;
    }
    __syncthreads();
    int n = tid >> 2, c = tid & 3;
    int row = row0 + n;
    if (row >= N_NODES) return;
    float acc = bfc[c];
#pragma unroll
    for (int k = 0; k < 64; ++k) acc = fmaf(ls[n * 65 + k], wl[k * 4 + c], acc);
    out[row * 4 + c] = acc;
}

// ---------------------------------------------------------------------------
extern "C" void kernel_launch(void* const* d_in, const int* in_sizes, int n_in,
                              void* d_out, int out_size, void* d_ws, size_t ws_size,
                              hipStream_t stream) {
    const float* x   = (const float*)d_in[0];
    const int*   ei  = (const int*)d_in[1];
    const float* W1  = (const float*)d_in[2];
    const float* b1  = (const float*)d_in[3];
    const float* W2  = (const float*)d_in[4];
    const float* b2  = (const float*)d_in[5];
    const float* Wfc = (const float*)d_in[6];
    const float* bfc = (const float*)d_in[7];
    float* out = (float*)d_out;

    float* deg  = (float*)d_ws;                 // N_NODES floats (padded to 102400)
    float* bufA = deg + 102400;                 // N*64
    float* bufB = bufA + N_NODES * 64;          // N*64

    const int* src = ei;
    const int* dst = ei + N_EDGES;

    // degrees (incl. self loop)
    k_deg_init<<<(N_NODES + 255) / 256, 256, 0, stream>>>(deg);
    k_deg_count<<<1024, 256, 0, stream>>>(dst, deg);

    // ---- layer 1: h = x @ W1 ; agg ; + b1 ----
    k_gemm<128, false><<<N_NODES / 16, 256, 0, stream>>>(x, W1, bufA);
    k_selfbias<<<(N_NODES * 64) / 256, 256, 0, stream>>>(bufA, deg, b1, bufB);
    k_edge<<<4096, 256, 0, stream>>>(src, dst, deg, bufA, bufB);

    // ---- layer 2: h = leaky(h1) @ W2 ; agg ; + b2 ----
    k_gemm<64, true><<<N_NODES / 16, 256, 0, stream>>>(bufB, W2, bufA);
    k_selfbias<<<(N_NODES * 64) / 256, 256, 0, stream>>>(bufA, deg, b2, bufB);
    k_edge<<<4096, 256, 0, stream>>>(src, dst, deg, bufA, bufB);

    // ---- final: out = h2 @ Wfc + bfc ----
    k_final<<<(N_NODES + 63) / 64, 256, 0, stream>>>(bufB, Wfc, bfc, out);
}

// Round 2
// 427.595 us; speedup vs baseline: 2.0511x; 2.0511x over previous
//
#include <hip/hip_runtime.h>

#define N_NODES 100000
#define N_EDGES 1600000
#define NEG_SLOPE 0.01f
#define NPAD 102400
#define NBLK_SCAN 391   // ceil(100000/256)

// ---------------------------------------------------------------------------
// deg[i] = 1 (self loop), then += 1 per incoming edge (dst). Int atomics.
// ---------------------------------------------------------------------------
__global__ void k_deg_init(int* __restrict__ deg) {
    int i = blockIdx.x * 256 + threadIdx.x;
    if (i < N_NODES) deg[i] = 1;
}

__global__ void k_deg_count(const int* __restrict__ dst, int* __restrict__ deg) {
    int idx = blockIdx.x * blockDim.x + threadIdx.x;
    int stride = gridDim.x * blockDim.x;
    for (int e = idx; e < N_EDGES; e += stride) atomicAdd(&deg[dst[e]], 1);
}

__global__ void k_dinv(const int* __restrict__ deg, float* __restrict__ dinv) {
    int i = blockIdx.x * 256 + threadIdx.x;
    if (i < N_NODES) dinv[i] = rsqrtf((float)deg[i]);
}

// ---------------------------------------------------------------------------
// Exclusive scan of in-degree (deg-1) into cur[]: 3-kernel block scan.
// ---------------------------------------------------------------------------
__global__ __launch_bounds__(256) void k_scan1(const int* __restrict__ deg,
                                               int* __restrict__ cur,
                                               int* __restrict__ bsum) {
    __shared__ int sd[256];
    int t = threadIdx.x;
    int gid = blockIdx.x * 256 + t;
    int v = (gid < N_NODES) ? (deg[gid] - 1) : 0;
    sd[t] = v;
    __syncthreads();
    for (int off = 1; off < 256; off <<= 1) {
        int add = (t >= off) ? sd[t - off] : 0;
        __syncthreads();
        sd[t] += add;
        __syncthreads();
    }
    cur[gid] = sd[t] - v;  // exclusive
    if (t == 255) bsum[blockIdx.x] = sd[255];
}

__global__ __launch_bounds__(512) void k_scan2(int* __restrict__ bsum) {
    __shared__ int sd[512];
    int t = threadIdx.x;
    int v = (t < NBLK_SCAN) ? bsum[t] : 0;
    sd[t] = v;
    __syncthreads();
    for (int off = 1; off < 512; off <<= 1) {
        int add = (t >= off) ? sd[t - off] : 0;
        __syncthreads();
        sd[t] += add;
        __syncthreads();
    }
    if (t < NBLK_SCAN) bsum[t] = sd[t] - v;  // exclusive
}

__global__ void k_scan3(int* __restrict__ cur, const int* __restrict__ bsum) {
    int gid = blockIdx.x * 256 + threadIdx.x;
    cur[gid] += bsum[blockIdx.x];
}

// ---------------------------------------------------------------------------
// CSR fill: slot = cur[dst]++ ; csr[slot] = src. After: cur[d] = end offset.
// ---------------------------------------------------------------------------
__global__ void k_fill(const int* __restrict__ src, const int* __restrict__ dst,
                       int* __restrict__ cur, int* __restrict__ csr) {
    int idx = blockIdx.x * blockDim.x + threadIdx.x;
    int stride = gridDim.x * blockDim.x;
    for (int e = idx; e < N_EDGES; e += stride) {
        int d = dst[e];
        int slot = atomicAdd(&cur[d], 1);
        csr[slot] = src[e];
    }
}

// ---------------------------------------------------------------------------
// Y[N,64] = (LEAKY? leaky(X) : X)[N,K] @ W[K,64]   (unchanged from R1)
// ---------------------------------------------------------------------------
template <int K, bool LEAKY>
__global__ __launch_bounds__(256) void k_gemm(const float* __restrict__ X,
                                              const float* __restrict__ W,
                                              float* __restrict__ Y) {
    __shared__ float ws[K * 64];
    __shared__ __align__(16) float xs[16][K];
    const int tid = threadIdx.x;
    for (int i = tid; i < K * 64; i += 256) ws[i] = W[i];
    const int row0 = blockIdx.x * 16;
    for (int i = tid; i < 16 * K; i += 256) {
        int r = i / K, k = i % K;
        float v = X[(row0 + r) * K + k];
        if (LEAKY) v = (v >= 0.f) ? v : NEG_SLOPE * v;
        xs[r][k] = v;
    }
    __syncthreads();
    const int c = tid & 63, rq = tid >> 6;
    float acc[4] = {0.f, 0.f, 0.f, 0.f};
    const float4* xs4 = reinterpret_cast<const float4*>(&xs[0][0]);
    for (int k = 0; k < K; k += 4) {
        float w0 = ws[(k + 0) * 64 + c];
        float w1 = ws[(k + 1) * 64 + c];
        float w2 = ws[(k + 2) * 64 + c];
        float w3 = ws[(k + 3) * 64 + c];
        const int kq = k >> 2;
#pragma unroll
        for (int j = 0; j < 4; ++j) {
            float4 xv = xs4[(rq * 4 + j) * (K / 4) + kq];
            acc[j] = fmaf(xv.x, w0, acc[j]);
            acc[j] = fmaf(xv.y, w1, acc[j]);
            acc[j] = fmaf(xv.z, w2, acc[j]);
            acc[j] = fmaf(xv.w, w3, acc[j]);
        }
    }
#pragma unroll
    for (int j = 0; j < 4; ++j)
        Y[(row0 + rq * 4 + j) * 64 + c] = acc[j];
}

// ---------------------------------------------------------------------------
// Node-parallel aggregation (no atomics). One wave per node, lane = feature.
// out[d,lane] = sum_{s in N(d)} h[s,lane]*dinv[s]*dinv[d]
//             + h[d,lane]/deg[d] + b[lane]
// cur[] holds post-fill inclusive end offsets: start = cur[d-1], end = cur[d].
// ---------------------------------------------------------------------------
__global__ __launch_bounds__(256) void k_agg(const int* __restrict__ cur,
                                             const int* __restrict__ csr,
                                             const float* __restrict__ dinv,
                                             const float* __restrict__ h,
                                             const float* __restrict__ b,
                                             float* __restrict__ out) {
    int node = blockIdx.x * 4 + (threadIdx.x >> 6);
    if (node >= N_NODES) return;
    int lane = threadIdx.x & 63;
    int start = (node == 0) ? 0 : cur[node - 1];
    int end = cur[node];
    start = __builtin_amdgcn_readfirstlane(start);
    end = __builtin_amdgcn_readfirstlane(end);
    float dv = dinv[node];
    float acc = h[(size_t)node * 64 + lane] * (dv * dv) + b[lane];
    int j = start;
    for (; j + 4 <= end; j += 4) {
        int s0 = csr[j], s1 = csr[j + 1], s2 = csr[j + 2], s3 = csr[j + 3];
        float w0 = dinv[s0] * dv, w1 = dinv[s1] * dv;
        float w2 = dinv[s2] * dv, w3 = dinv[s3] * dv;
        float h0 = h[(size_t)s0 * 64 + lane];
        float h1 = h[(size_t)s1 * 64 + lane];
        float h2 = h[(size_t)s2 * 64 + lane];
        float h3 = h[(size_t)s3 * 64 + lane];
        acc = fmaf(h0, w0, acc);
        acc = fmaf(h1, w1, acc);
        acc = fmaf(h2, w2, acc);
        acc = fmaf(h3, w3, acc);
    }
    for (; j < end; ++j) {
        int s = csr[j];
        acc = fmaf(h[(size_t)s * 64 + lane], dinv[s] * dv, acc);
    }
    out[(size_t)node * 64 + lane] = acc;
}

// ---------------------------------------------------------------------------
// out[N,4] = H[N,64] @ Wfc[64,4] + bfc   (unchanged from R1)
// ---------------------------------------------------------------------------
__global__ __launch_bounds__(256) void k_final(const float* __restrict__ H,
                                               const float* __restrict__ Wfc,
                                               const float* __restrict__ bfc,
                                               float* __restrict__ out) {
    __shared__ float ls[64 * 65];
    __shared__ float wl[64 * 4];
    const int tid = threadIdx.x;
    const int row0 = blockIdx.x * 64;
    for (int i = tid; i < 64 * 4; i += 256) wl[i] = Wfc[i];
    for (int i = tid; i < 64 * 64; i += 256) {
        int r = i >> 6, k = i & 63;
        int row = row0 + r;
        ls[r * 65 + k] = (row < N_NODES) ? H[row * 64 + k] : 0.f;
    }
    __syncthreads();
    int n = tid >> 2, c = tid & 3;
    int row = row0 + n;
    if (row >= N_NODES) return;
    float acc = bfc[c];
#pragma unroll
    for (int k = 0; k < 64; ++k) acc = fmaf(ls[n * 65 + k], wl[k * 4 + c], acc);
    out[row * 4 + c] = acc;
}

// ---------------------------------------------------------------------------
extern "C" void kernel_launch(void* const* d_in, const int* in_sizes, int n_in,
                              void* d_out, int out_size, void* d_ws, size_t ws_size,
                              hipStream_t stream) {
    const float* x   = (const float*)d_in[0];
    const int*   ei  = (const int*)d_in[1];
    const float* W1  = (const float*)d_in[2];
    const float* b1  = (const float*)d_in[3];
    const float* W2  = (const float*)d_in[4];
    const float* b2  = (const float*)d_in[5];
    const float* Wfc = (const float*)d_in[6];
    const float* bfc = (const float*)d_in[7];
    float* out = (float*)d_out;

    // workspace layout (4B elements)
    int*   deg  = (int*)d_ws;                        // NPAD
    int*   cur  = deg + NPAD;                        // NPAD
    float* dinv = (float*)(cur + NPAD);              // NPAD
    int*   bsum = (int*)(dinv + NPAD);               // 1024
    int*   csr  = bsum + 1024;                       // N_EDGES (pad 1600512)
    float* bufA = (float*)(csr + 1600512);           // N*64
    float* bufB = bufA + N_NODES * 64;               // N*64

    const int* src = ei;
    const int* dst = ei + N_EDGES;

    // degree (incl. self loop) + dinv
    k_deg_init<<<(N_NODES + 255) / 256, 256, 0, stream>>>(deg);
    k_deg_count<<<2048, 256, 0, stream>>>(dst, deg);
    k_dinv<<<(N_NODES + 255) / 256, 256, 0, stream>>>(deg, dinv);

    // CSR build: exclusive scan of in-degree, then cursor fill
    k_scan1<<<NBLK_SCAN, 256, 0, stream>>>(deg, cur, bsum);
    k_scan2<<<1, 512, 0, stream>>>(bsum);
    k_scan3<<<NBLK_SCAN, 256, 0, stream>>>(cur, bsum);
    k_fill<<<2048, 256, 0, stream>>>(src, dst, cur, csr);

    // ---- layer 1 ----
    k_gemm<128, false><<<N_NODES / 16, 256, 0, stream>>>(x, W1, bufA);
    k_agg<<<(N_NODES + 3) / 4, 256, 0, stream>>>(cur, csr, dinv, bufA, b1, bufB);

    // ---- layer 2 ----
    k_gemm<64, true><<<N_NODES / 16, 256, 0, stream>>>(bufB, W2, bufA);
    k_agg<<<(N_NODES + 3) / 4, 256, 0, stream>>>(cur, csr, dinv, bufA, b2, bufB);

    // ---- final FC ----
    k_final<<<(N_NODES + 63) / 64, 256, 0, stream>>>(bufB, Wfc, bfc, out);
}